// Round 4
// baseline (828.126 us; speedup 1.0000x reference)
//
#include <hip/hip_runtime.h>

typedef _Float16 hv8 __attribute__((ext_vector_type(8)));  // 8 fp16 = 4 VGPRs MFMA A/B frag
typedef float    fv4 __attribute__((ext_vector_type(4)));  // 4 fp32 MFMA C/D frag

#define DEVI __device__ __forceinline__

static constexpr int T_ = 200;
static constexpr int WS = 72;          // row stride (halfs) for weight rows and A-slabs: 2-way bank alias max
static constexpr int SLAB = 3 * 16 * WS; // 3456 halfs per wave (A1,A2,A3 16 rows each)

DEVI float fsig(float x)  { return 1.0f / (1.0f + __expf(-x)); }                        // inf-safe -> 0/1
DEVI float ftanh(float x) { float e = __expf(2.0f * x); return 1.0f - 2.0f / (e + 1.0f); } // -> -1/1

DEVI float lstm_unit(float ci, float cf, float cg, float co, float& c) {
    float gi = fsig(ci), gf = fsig(cf), gg = ftanh(cg), go = fsig(co);
    c = gf * c + gi * gg;
    return go * ftanh(c);
}

// One wave = 4 batch rows, full 3-layer pipeline, sync-free main loop (wave-private LDS slab).
// 256 blocks x 256 threads = 1024 waves = 1 wave/SIMD on all 256 CUs.
__global__ __launch_bounds__(256, 1) void lstm_fused(
    const float* __restrict__ xg,
    const float* __restrict__ Wih1, const float* __restrict__ Whh1,
    const float* __restrict__ bih1, const float* __restrict__ bhh1,
    const float* __restrict__ Wih2, const float* __restrict__ Whh2,
    const float* __restrict__ bih2, const float* __restrict__ bhh2,
    const float* __restrict__ Wih3, const float* __restrict__ Whh3,
    const float* __restrict__ bih3, const float* __restrict__ bhh3,
    const float* __restrict__ W_fc1, const float* __restrict__ b_fc1,
    const float* __restrict__ W_fc2, const float* __restrict__ b_fc2,
    const float* __restrict__ W_cls, const float* __restrict__ b_cls,
    float* __restrict__ outp)
{
    // poolH: weight rows [256][WS] fp16 during prologue; per-wave A-slabs carved afterwards.
    __shared__ __align__(16) _Float16 poolH[256 * WS];   // 36864 B
    __shared__ float T2s[512];   // [32][16] = W_fc2 @ W_fc1
    __shared__ float t2vs[32];   // b_fc2 + W_fc2 @ b_fc1
    __shared__ float Msh[96];    // [16][6] collapsed head matrix
    __shared__ float vsh[6];     // collapsed head bias

    const int tid  = threadIdx.x;
    const int wid  = tid >> 6;
    const int lane = tid & 63;
    const int nl   = lane & 15;
    const int quad = lane >> 4;
    const int b0   = (blockIdx.x * 4 + wid) * 4;   // 4 batch rows per wave

    // ---- stage all weights as B^T rows [n][k] fp16. n: 0-63 L1, 64-191 L2, 192-255 L3.
    // K layouts: L1 [x(0:36)|0|h1(48:64)]  L2 [h1(0:16)|h2(16:48)|0]  L3 [h2(0:32)|h3(32:48)|0]
    for (int idx = tid; idx < 256 * WS; idx += 256) {
        int n = idx / WS, k = idx - n * WS;
        float v = 0.f;
        if (k < 64) {
            if (n < 64) {
                if (k < 36)      v = Wih1[n * 36 + k];
                else if (k >= 48) v = Whh1[n * 16 + (k - 48)];
            } else if (n < 192) {
                int row = n - 64;                      // g*32 + unit
                if (k < 16)      v = Wih2[row * 16 + k];
                else if (k < 48) v = Whh2[row * 32 + (k - 16)];
            } else {
                int row = n - 192;
                if (k < 32)      v = Wih3[row * 32 + k];
                else if (k < 48) v = Whh3[row * 16 + (k - 32)];
            }
        }
        poolH[idx] = (_Float16)v;
    }
    // head: T2 = W_fc2 @ W_fc1
    for (int idx = tid; idx < 512; idx += 256) {
        int b = idx >> 4, u = idx & 15;
        float acc = 0.f;
        for (int a = 0; a < 128; ++a) acc += W_fc2[b * 128 + a] * W_fc1[a * 16 + u];
        T2s[idx] = acc;
    }
    if (tid < 32) {
        float acc = b_fc2[tid];
        for (int a = 0; a < 128; ++a) acc += W_fc2[tid * 128 + a] * b_fc1[a];
        t2vs[tid] = acc;
    }
    __syncthreads();

    // ---- every wave loads ALL B-frags (L1:8, L2:16, L3:8) into registers ----
    hv8 B1[2][4], B2[2][8], B3[2][4];
    #pragma unroll
    for (int kt = 0; kt < 2; ++kt) {
        int ko = kt * 32 + quad * 8;
        #pragma unroll
        for (int nt = 0; nt < 4; ++nt)
            B1[kt][nt] = *(const hv8*)&poolH[(nt * 16 + nl) * WS + ko];
        #pragma unroll
        for (int nt = 0; nt < 8; ++nt)
            B2[kt][nt] = *(const hv8*)&poolH[(64 + (nt >> 1) * 32 + (nt & 1) * 16 + nl) * WS + ko];
        #pragma unroll
        for (int nt = 0; nt < 4; ++nt)
            B3[kt][nt] = *(const hv8*)&poolH[(192 + nt * 16 + nl) * WS + ko];
    }
    float b1r[4], b2r[8], b3r[4];
    #pragma unroll
    for (int g = 0; g < 4; ++g) b1r[g] = bih1[g * 16 + nl] + bhh1[g * 16 + nl];
    #pragma unroll
    for (int nt = 0; nt < 8; ++nt) {
        int row = (nt >> 1) * 32 + (nt & 1) * 16 + nl;
        b2r[nt] = bih2[row] + bhh2[row];
    }
    #pragma unroll
    for (int g = 0; g < 4; ++g) b3r[g] = bih3[g * 16 + nl] + bhh3[g * 16 + nl];
    // collapsed head: M[u][j] = sum_b Wc[j][b]*T2[b][u];  v[j] = bc[j] + sum_b Wc[j][b]*t2v[b]
    if (tid < 96) {
        int u = tid / 6, j = tid - (tid / 6) * 6;
        float acc = 0.f;
        for (int b = 0; b < 32; ++b) acc += W_cls[j * 32 + b] * T2s[b * 16 + u];
        Msh[u * 6 + j] = acc;
    }
    if (tid < 6) {
        float acc = b_cls[tid];
        for (int b = 0; b < 32; ++b) acc += W_cls[tid * 32 + b] * t2vs[b];
        vsh[tid] = acc;
    }
    __syncthreads();   // LAST barrier: weights in regs, shared head arrays final. Loop is sync-free.

    // ---- wave-private A-slab (carved from poolH), zero it (h(-1)=0, pads=0) ----
    _Float16* slab = poolH + wid * SLAB;
    _Float16* A1 = slab;               // [16][WS]: x(0:36) | h1(48:64)
    _Float16* A2 = slab + 16 * WS;     // [16][WS]: h1(0:16) | h2(16:48)
    _Float16* A3 = slab + 32 * WS;     // [16][WS]: h2(0:32) | h3(32:48)
    {
        unsigned long long* z = (unsigned long long*)slab;   // 3456 halfs = 864 u64
        #pragma unroll
        for (int i = 0; i < 14; ++i) {
            int idx = lane + i * 64;
            if (idx < 864) z[idx] = 0ull;
        }
    }
    // per-lane x-staging slots: idx = lane + i*64 < 144 -> (row, f)
    int   xrow[3], xldso[3];
    bool  xvld[3];
    const float* xp[3];
    #pragma unroll
    for (int i = 0; i < 3; ++i) {
        int idx = lane + i * 64;
        xvld[i] = idx < 144;
        int row = idx / 36, f = idx - (idx / 36) * 36;
        xrow[i] = row; xldso[i] = row * WS + f;
        xp[i] = xg + ((size_t)(b0 + row) * T_) * 36 + f;   // t=0
    }
    // stage x(0)
    #pragma unroll
    for (int i = 0; i < 3; ++i)
        if (xvld[i]) A1[xldso[i]] = (_Float16)xp[i][0];
    #pragma unroll
    for (int i = 0; i < 3; ++i) xp[i] += 36;               // now at t=1

    float c1[4] = {0,0,0,0}, c2[8] = {0,0,0,0,0,0,0,0}, c3[4] = {0,0,0,0};
    float hfin[4] = {0,0,0,0};

    for (int s = 0; s < T_; ++s) {
        // issue x(s+1) loads now; consumed (cvt+LDS write) at iteration bottom
        float xr[3];
        bool pf = (s + 1 < T_);
        if (pf) {
            #pragma unroll
            for (int i = 0; i < 3; ++i) if (xvld[i]) xr[i] = *xp[i];
        }
        // ---- L1: [x | h1] @ W1 ----
        {
            hv8 a0 = *(const hv8*)&A1[nl * WS +      quad * 8];
            hv8 a1 = *(const hv8*)&A1[nl * WS + 32 + quad * 8];
            fv4 C[4];
            #pragma unroll
            for (int nt = 0; nt < 4; ++nt) { float b = b1r[nt]; C[nt] = (fv4){b,b,b,b}; }
            #pragma unroll
            for (int nt = 0; nt < 4; ++nt) C[nt] = __builtin_amdgcn_mfma_f32_16x16x32_f16(a0, B1[0][nt], C[nt], 0, 0, 0);
            #pragma unroll
            for (int nt = 0; nt < 4; ++nt) C[nt] = __builtin_amdgcn_mfma_f32_16x16x32_f16(a1, B1[1][nt], C[nt], 0, 0, 0);
            #pragma unroll
            for (int r = 0; r < 4; ++r) {
                int m = quad * 4 + r;
                float c = c1[r];
                float h = lstm_unit(C[0][r], C[1][r], C[2][r], C[3][r], c);
                c1[r] = c;
                _Float16 hh = (_Float16)h;
                A1[m * WS + 48 + nl] = hh;     // own recurrence
                A2[m * WS + nl]      = hh;     // feed L2
            }
        }
        // ---- L2: [h1 | h2] @ W2 ----
        {
            hv8 a0 = *(const hv8*)&A2[nl * WS +      quad * 8];
            hv8 a1 = *(const hv8*)&A2[nl * WS + 32 + quad * 8];
            fv4 D[8];
            #pragma unroll
            for (int nt = 0; nt < 8; ++nt) { float b = b2r[nt]; D[nt] = (fv4){b,b,b,b}; }
            #pragma unroll
            for (int nt = 0; nt < 8; ++nt) D[nt] = __builtin_amdgcn_mfma_f32_16x16x32_f16(a0, B2[0][nt], D[nt], 0, 0, 0);
            #pragma unroll
            for (int nt = 0; nt < 8; ++nt) D[nt] = __builtin_amdgcn_mfma_f32_16x16x32_f16(a1, B2[1][nt], D[nt], 0, 0, 0);
            #pragma unroll
            for (int half = 0; half < 2; ++half)
                #pragma unroll
                for (int r = 0; r < 4; ++r) {
                    int m = quad * 4 + r;
                    float c = c2[half * 4 + r];
                    float h = lstm_unit(D[0+half][r], D[2+half][r], D[4+half][r], D[6+half][r], c);
                    c2[half * 4 + r] = c;
                    _Float16 hh = (_Float16)h;
                    int uu = half * 16 + nl;
                    A2[m * WS + 16 + uu] = hh;  // own recurrence
                    A3[m * WS + uu]      = hh;  // feed L3
                }
        }
        // ---- L3: [h2 | h3] @ W3 ----
        {
            hv8 a0 = *(const hv8*)&A3[nl * WS +      quad * 8];
            hv8 a1 = *(const hv8*)&A3[nl * WS + 32 + quad * 8];
            fv4 C[4];
            #pragma unroll
            for (int nt = 0; nt < 4; ++nt) { float b = b3r[nt]; C[nt] = (fv4){b,b,b,b}; }
            #pragma unroll
            for (int nt = 0; nt < 4; ++nt) C[nt] = __builtin_amdgcn_mfma_f32_16x16x32_f16(a0, B3[0][nt], C[nt], 0, 0, 0);
            #pragma unroll
            for (int nt = 0; nt < 4; ++nt) C[nt] = __builtin_amdgcn_mfma_f32_16x16x32_f16(a1, B3[1][nt], C[nt], 0, 0, 0);
            #pragma unroll
            for (int r = 0; r < 4; ++r) {
                int m = quad * 4 + r;
                float c = c3[r];
                float h = lstm_unit(C[0][r], C[1][r], C[2][r], C[3][r], c);
                c3[r] = c;
                hfin[r] = h;                    // last iteration's value = h3(T-1)
                A3[m * WS + 32 + nl] = (_Float16)h;
            }
        }
        // ---- write x(s+1) into A1 (after this step's L1 frag reads; in-wave DS order) ----
        if (pf) {
            #pragma unroll
            for (int i = 0; i < 3; ++i)
                if (xvld[i]) { A1[xldso[i]] = (_Float16)xr[i]; xp[i] += 36; }
        }
    }

    // ---- epilogue (wave-local): out[b][j] = h3 . M[:,j] + v[j] ----
    float* hsF = (float*)slab;     // reuse slab as [4][16] fp32
    if (quad == 0) {
        #pragma unroll
        for (int r = 0; r < 4; ++r) hsF[r * 16 + nl] = hfin[r];
    }
    if (lane < 24) {
        int row = lane / 6, j = lane - (lane / 6) * 6;
        float acc = vsh[j];
        #pragma unroll
        for (int u = 0; u < 16; ++u) acc += hsF[row * 16 + u] * Msh[u * 6 + j];
        outp[(b0 + row) * 6 + j] = acc;
    }
}

extern "C" void kernel_launch(void* const* d_in, const int* in_sizes, int n_in,
                              void* d_out, int out_size, void* d_ws, size_t ws_size,
                              hipStream_t stream) {
    const float* x     = (const float*)d_in[0];
    const float* Wih1  = (const float*)d_in[1];
    const float* Whh1  = (const float*)d_in[2];
    const float* bih1  = (const float*)d_in[3];
    const float* bhh1  = (const float*)d_in[4];
    const float* Wih2  = (const float*)d_in[5];
    const float* Whh2  = (const float*)d_in[6];
    const float* bih2  = (const float*)d_in[7];
    const float* bhh2  = (const float*)d_in[8];
    const float* Wih3  = (const float*)d_in[9];
    const float* Whh3  = (const float*)d_in[10];
    const float* bih3  = (const float*)d_in[11];
    const float* bhh3  = (const float*)d_in[12];
    const float* W_fc1 = (const float*)d_in[13];
    const float* b_fc1 = (const float*)d_in[14];
    const float* W_fc2 = (const float*)d_in[15];
    const float* b_fc2 = (const float*)d_in[16];
    const float* W_cls = (const float*)d_in[17];
    const float* b_cls = (const float*)d_in[18];

    lstm_fused<<<256, 256, 0, stream>>>(x,
        Wih1, Whh1, bih1, bhh1,
        Wih2, Whh2, bih2, bhh2,
        Wih3, Whh3, bih3, bhh3,
        W_fc1, b_fc1, W_fc2, b_fc2, W_cls, b_cls,
        (float*)d_out);
}

// Round 5
// 484.002 us; speedup vs baseline: 1.7110x; 1.7110x over previous
//
#include <hip/hip_runtime.h>

typedef _Float16 hv8 __attribute__((ext_vector_type(8)));  // 8 fp16 = 4 VGPRs MFMA A/B frag
typedef float    fv4 __attribute__((ext_vector_type(4)));  // 4 fp32 MFMA C/D frag

#define DEVI __device__ __forceinline__

static constexpr int T_   = 200;
static constexpr int ROWS = 8;      // real batch rows per block (512 blocks, 2 blocks/CU)
static constexpr int WS   = 72;     // row stride in halfs (144 B: 16B-aligned, 2-way bank alias = free)
// A-slab offsets in halfs (carved into weight pool after B-frags move to registers)
static constexpr int A1o = 0;                 // [16][WS]: x(0:36) | bias1(36)=1 | pad | h1(48:64)
static constexpr int A2o = 16 * WS;           // [2][16][WS]: h1(0:16) | h2(16:48) | bias(48)=1 | pad
static constexpr int A3o = A2o + 2 * 16 * WS; // [2][16][WS]: h2(0:32) | h3(32:48) | bias(48)=1 | pad
static constexpr int A_TOTAL = A3o + 2 * 16 * WS;  // 5760 halfs

#if __has_builtin(__builtin_amdgcn_rcpf)
DEVI float frcp(float x) { return __builtin_amdgcn_rcpf(x); }
#else
DEVI float frcp(float x) { return 1.0f / x; }
#endif
DEVI float fsig(float x)  { return frcp(1.0f + __expf(-x)); }                          // inf-safe -> 0/1
DEVI float ftanh(float x) { float e = __expf(2.0f * x); return 1.0f - 2.0f * frcp(e + 1.0f); } // -> -1/1

DEVI unsigned int pk2h(float a, float b) {     // pack two fp32 -> fp16x2 (RNE via v_cvt_f16_f32)
    union { _Float16 h[2]; unsigned int u; } cv;
    cv.h[0] = (_Float16)a; cv.h[1] = (_Float16)b;
    return cv.u;
}

// ---------------- fused 3-layer LSTM + collapsed linear head ----------------
// 512 blocks x 256 threads; block owns 8 batch rows; 4 waves = layer pipeline stages
// (w0: L1(t=s), w1/w2: L2(t=s-1) unit-halves, w3: L3(t=s-2)); one barrier per step.
__global__ __launch_bounds__(256, 2) void lstm_fused(
    const float* __restrict__ xg,
    const float* __restrict__ Wih1, const float* __restrict__ Whh1,
    const float* __restrict__ bih1, const float* __restrict__ bhh1,
    const float* __restrict__ Wih2, const float* __restrict__ Whh2,
    const float* __restrict__ bih2, const float* __restrict__ bhh2,
    const float* __restrict__ Wih3, const float* __restrict__ Whh3,
    const float* __restrict__ bih3, const float* __restrict__ bhh3,
    const float* __restrict__ W_fc1, const float* __restrict__ b_fc1,
    const float* __restrict__ W_fc2, const float* __restrict__ b_fc2,
    const float* __restrict__ W_cls, const float* __restrict__ b_cls,
    float* __restrict__ outp)
{
    // poolH: weights [256 rows][WS] fp16 during prologue; A-slabs carved in afterwards
    __shared__ __align__(16) _Float16 poolH[256 * WS];       // 36864 B
    __shared__ unsigned int xst[2 * 16 * ROWS * 18];         // x chunks fp16x2-packed: [par][t&15][row][18]
    __shared__ float T2s[512];   // [32][16] = W_fc2 @ W_fc1
    __shared__ float t2vs[32];   // b_fc2 + W_fc2 @ b_fc1
    __shared__ float Msh[96];    // [16][6] collapsed head matrix
    __shared__ float vsh[6];     // collapsed head bias

    const int tid  = threadIdx.x;
    const int wid  = tid >> 6;       // 0=L1, 1/2=L2 halves, 3=L3
    const int lane = tid & 63;
    const int nl   = lane & 15;
    const int quad = lane >> 4;
    const int b0   = blockIdx.x * ROWS;

    // ---- stage weights (fp32 -> fp16) as B^T rows [n][k]; bias folded in as a weight column ----
    // w0 (L1): k = [Wih1(0:36) | bias(36) | 0 | Whh1(48:64)]
    // w1/w2 (L2 half): k = [Wih2(0:16) | Whh2(16:48) | bias(48) | 0]
    // w3 (L3): k = [Wih3(0:32) | Whh3(32:48) | bias(48) | 0]
    for (int idx = tid; idx < 256 * WS; idx += 256) {
        int n = idx / WS, k = idx - n * WS;
        int w = n >> 6, r = n & 63;
        int g = r >> 4, u = r & 15;
        float v = 0.f;
        if (w == 0) {
            int row = g * 16 + u;
            if (k < 36)       v = Wih1[row * 36 + k];
            else if (k == 36) v = bih1[row] + bhh1[row];
            else if (k >= 48 && k < 64) v = Whh1[row * 16 + (k - 48)];
        } else if (w <= 2) {
            int row = g * 32 + (w - 1) * 16 + u;
            if (k < 16)       v = Wih2[row * 16 + k];
            else if (k < 48)  v = Whh2[row * 32 + (k - 16)];
            else if (k == 48) v = bih2[row] + bhh2[row];
        } else {
            int row = g * 16 + u;
            if (k < 32)       v = Wih3[row * 32 + k];
            else if (k < 48)  v = Whh3[row * 16 + (k - 32)];
            else if (k == 48) v = bih3[row] + bhh3[row];
        }
        poolH[idx] = (_Float16)v;
    }
    // head: T2 = W_fc2 @ W_fc1 (fp32; 24KB weights, L2-resident)
    for (int idx = tid; idx < 512; idx += 256) {
        int b = idx >> 4, u = idx & 15;
        float acc = 0.f;
        for (int a = 0; a < 128; ++a) acc += W_fc2[b * 128 + a] * W_fc1[a * 16 + u];
        T2s[idx] = acc;
    }
    if (tid < 32) {
        float acc = b_fc2[tid];
        for (int a = 0; a < 128; ++a) acc += W_fc2[tid * 128 + a] * b_fc1[a];
        t2vs[tid] = acc;
    }
    __syncthreads();

    // ---- per-wave register-resident B-frags: lane holds B[k=kt*32+quad*8+j][n=nt*16+nl] ----
    hv8 Bf[2][4];
    #pragma unroll
    for (int kt = 0; kt < 2; ++kt)
        #pragma unroll
        for (int nt = 0; nt < 4; ++nt)
            Bf[kt][nt] = *(const hv8*)&poolH[(wid * 64 + nt * 16 + nl) * WS + kt * 32 + quad * 8];
    // collapsed head: M[u][j] = sum_b Wc[j][b]*T2[b][u];  v[j] = bc[j] + sum_b Wc[j][b]*t2v[b]
    if (tid < 96) {
        int u = tid / 6, j = tid - (tid / 6) * 6;
        float acc = 0.f;
        for (int b = 0; b < 32; ++b) acc += W_cls[j * 32 + b] * T2s[b * 16 + u];
        Msh[u * 6 + j] = acc;
    }
    if (tid < 6) {
        float acc = b_cls[tid];
        for (int b = 0; b < 32; ++b) acc += W_cls[tid * 32 + b] * t2vs[b];
        vsh[tid] = acc;
    }
    __syncthreads();   // weights now in registers; pool reusable

    // ---- zero A-slabs, set bias-1.0 columns, stage x chunk 0 ----
    for (int idx = tid; idx < A_TOTAL; idx += 256) poolH[idx] = (_Float16)0.f;
    {   // refill chunk 0 (t=0..15)
        const float2* xw2 = (const float2*)xg;
        #pragma unroll
        for (int i = 0; i < 9; ++i) {
            int j = tid + i * 256;                  // < 2304 = 8 rows * 16 t * 18
            int row = j / 288, rem = j - row * 288;
            int tl = rem / 18, p = rem - tl * 18;
            float2 xv = xw2[((size_t)(b0 + row) * T_ + tl) * 18 + p];
            xst[(tl * ROWS + row) * 18 + p] = pk2h(xv.x, xv.y);
        }
    }
    __syncthreads();
    // bias columns (all 16 M-rows, both parities) + x(0) into A1
    if (tid < 16)  poolH[A1o + tid * WS + 36] = (_Float16)1.0f;
    if (tid < 64) {
        int buf = tid >> 5, par = (tid >> 4) & 1, row = tid & 15;
        poolH[(buf ? A3o : A2o) + par * 16 * WS + row * WS + 48] = (_Float16)1.0f;
    }
    if (tid < ROWS * 18) {   // u32 view: A1 row stride = WS/2 = 36
        int row = tid / 18, p = tid - (tid / 18) * 18;
        ((unsigned int*)poolH)[row * 36 + p] = xst[(0 * ROWS + row) * 18 + p];
    }
    __syncthreads();

    float c_st[4] = {0.f, 0.f, 0.f, 0.f};  // fp32 cell state: 4 M-rows x 1 unit per lane

    for (int s = 0; s < T_ + 2; ++s) {
        const int rd = (s - 1) & 1, wr = s & 1;
        // chunk refill: at interval start stage chunk (s/16 + 1) into other parity;
        // loads drain at this step's end barrier, hidden under compute.
        if ((s & 15) == 0) {
            int cn = (s >> 4) + 1;
            if (cn <= 12) {
                const float2* xw2 = (const float2*)xg;
                unsigned int* dst = &xst[(cn & 1) * 16 * ROWS * 18];
                int tbase = cn * 16;
                #pragma unroll
                for (int i = 0; i < 9; ++i) {
                    int j = tid + i * 256;
                    int row = j / 288, rem = j - row * 288;
                    int tl = rem / 18, p = rem - tl * 18;
                    int t = tbase + tl;
                    if (t < T_) {
                        float2 xv = xw2[((size_t)(b0 + row) * T_ + t) * 18 + p];
                        dst[(tl * ROWS + row) * 18 + p] = pk2h(xv.x, xv.y);
                    }
                }
            }
        }
        bool act;
        if (wid == 0)      act = (s < T_);                 // L1 at t=s
        else if (wid <= 2) act = (s >= 1 && s <= T_);      // L2 at t=s-1
        else               act = (s >= 2);                 // L3 at t=s-2
        if (act) {
            int abase;
            if (wid == 0)      abase = A1o;
            else if (wid <= 2) abase = A2o + rd * 16 * WS;
            else               abase = A3o + rd * 16 * WS;
            hv8 a0 = *(const hv8*)&poolH[abase + nl * WS +      quad * 8];
            hv8 a1 = *(const hv8*)&poolH[abase + nl * WS + 32 + quad * 8];
            // wave0: copy x(s+1) xstage -> A1 (after own frag reads; in-wave LDS order)
            if (wid == 0 && s + 1 < T_) {
                int t = s + 1;
                const unsigned int* src = &xst[((t >> 4) & 1) * 16 * ROWS * 18 + (t & 15) * ROWS * 18];
                unsigned int* dstA = (unsigned int*)poolH;
                #pragma unroll
                for (int i = 0; i < 3; ++i) {
                    int idx = i * 64 + lane;
                    if (idx < ROWS * 18) {
                        int row = idx / 18, p = idx - (idx / 18) * 18;
                        dstA[row * 36 + p] = src[idx];
                    }
                }
            }
            fv4 C[4] = {(fv4){0,0,0,0}, (fv4){0,0,0,0}, (fv4){0,0,0,0}, (fv4){0,0,0,0}};
            #pragma unroll
            for (int nt = 0; nt < 4; ++nt) C[nt] = __builtin_amdgcn_mfma_f32_16x16x32_f16(a0, Bf[0][nt], C[nt], 0, 0, 0);
            #pragma unroll
            for (int nt = 0; nt < 4; ++nt) C[nt] = __builtin_amdgcn_mfma_f32_16x16x32_f16(a1, Bf[1][nt], C[nt], 0, 0, 0);
            // C[nt][r] = gate nt (i,f,g,o) for M-row quad*4+r, unit nl (bias included via 1.0-column)
            #pragma unroll
            for (int r = 0; r < 4; ++r) {
                int m = quad * 4 + r;
                float gi = fsig(C[0][r]);
                float gf = fsig(C[1][r]);
                float gg = ftanh(C[2][r]);
                float go = fsig(C[3][r]);
                float c  = gf * c_st[r] + gi * gg;
                c_st[r] = c;
                _Float16 hh = (_Float16)(go * ftanh(c));
                if (wid == 0) {
                    poolH[A1o + m * WS + 48 + nl] = hh;                    // own recurrence
                    poolH[A2o + wr * 16 * WS + m * WS + nl] = hh;          // feed L2
                } else if (wid <= 2) {
                    int ug = (wid - 1) * 16 + nl;
                    poolH[A2o + wr * 16 * WS + m * WS + 16 + ug] = hh;     // own recurrence
                    poolH[A3o + wr * 16 * WS + m * WS + ug] = hh;          // feed L3
                } else {
                    poolH[A3o + wr * 16 * WS + m * WS + 32 + nl] = hh;     // own recurrence
                }
            }
        }
        __syncthreads();
    }

    // ---- epilogue: out[b][j] = h3(T-1) . M[:,j] + v[j]  (h3 in A3 parity (T_+1)&1) ----
    if (tid < ROWS * 6) {
        int row = tid / 6, j = tid - (tid / 6) * 6;
        float acc = vsh[j];
        const int hb = A3o + ((T_ + 1) & 1) * 16 * WS + row * WS + 32;
        #pragma unroll
        for (int u = 0; u < 16; ++u)
            acc += (float)poolH[hb + u] * Msh[u * 6 + j];
        outp[(b0 + row) * 6 + j] = acc;
    }
}

extern "C" void kernel_launch(void* const* d_in, const int* in_sizes, int n_in,
                              void* d_out, int out_size, void* d_ws, size_t ws_size,
                              hipStream_t stream) {
    const float* x     = (const float*)d_in[0];
    const float* Wih1  = (const float*)d_in[1];
    const float* Whh1  = (const float*)d_in[2];
    const float* bih1  = (const float*)d_in[3];
    const float* bhh1  = (const float*)d_in[4];
    const float* Wih2  = (const float*)d_in[5];
    const float* Whh2  = (const float*)d_in[6];
    const float* bih2  = (const float*)d_in[7];
    const float* bhh2  = (const float*)d_in[8];
    const float* Wih3  = (const float*)d_in[9];
    const float* Whh3  = (const float*)d_in[10];
    const float* bih3  = (const float*)d_in[11];
    const float* bhh3  = (const float*)d_in[12];
    const float* W_fc1 = (const float*)d_in[13];
    const float* b_fc1 = (const float*)d_in[14];
    const float* W_fc2 = (const float*)d_in[15];
    const float* b_fc2 = (const float*)d_in[16];
    const float* W_cls = (const float*)d_in[17];
    const float* b_cls = (const float*)d_in[18];

    lstm_fused<<<512, 256, 0, stream>>>(x,
        Wih1, Whh1, bih1, bhh1,
        Wih2, Whh2, bih2, bhh2,
        Wih3, Whh3, bih3, bhh3,
        W_fc1, b_fc1, W_fc2, b_fc2, W_cls, b_cls,
        (float*)d_out);
}